// Round 7
// baseline (271.143 us; speedup 1.0000x reference)
//
#include <hip/hip_runtime.h>
#include <hip/hip_cooperative_groups.h>
#include <cstdint>

namespace cg = cooperative_groups;

#define NPTS   16384
#define BATCH  4
#define BNP    65536
#define CIN    64
#define KNB    16
#define COUT   128
#define NGRP   (BNP / KNB)     // 4096 groups of 16 points
#define GRIDMAX 512
#define BN_EPS 1e-5f

typedef __attribute__((ext_vector_type(8))) short     short8;
typedef __attribute__((ext_vector_type(4))) float     f32x4;
typedef __attribute__((ext_vector_type(2))) unsigned  u32x2;
typedef __attribute__((ext_vector_type(4))) int       i32x4;

// wait until <= n vector-memory ops outstanding (lgkm=15, exp=7 = no wait)
#define WAITVM(n) __builtin_amdgcn_s_waitcnt(0x0F70 | (n))

__device__ __forceinline__ unsigned short f2bf(float f) {   // RNE
    unsigned u = __float_as_uint(f);
    u += 0x7FFFu + ((u >> 16) & 1u);
    return (unsigned short)(u >> 16);
}
__device__ __forceinline__ float bf2f(unsigned short h) {
    return __uint_as_float(((unsigned)h) << 16);
}

union SharedAB {                     // phase A transpose tile / phase B spir dbuf
    float t[CIN][CIN + 1];           // 16.6 KB (union max)
    unsigned short spir[4][2][1024]; // 16 KB: 4 waves x 2-deep x 2KB (R2-proven)
};

// One cooperative kernel, LDS ~27.9 KB -> 2 blocks/CU under the 64 KB
// cooperative-occupancy model. All phases gridDim-stride so any co-resident
// grid size is correct.
__global__ __launch_bounds__(256, 2) void k_all(
    const float* __restrict__ feat, const int* __restrict__ nidx,
    const float* __restrict__ Wm,   const float* __restrict__ Wc,
    const float* __restrict__ gamma,const float* __restrict__ beta,
    unsigned short* __restrict__ fb, float* __restrict__ part,
    float* __restrict__ scalesh,     float* __restrict__ out)
{
    __shared__ __align__(16) SharedAB u;                      // 16.6 KB
    __shared__ __align__(16) unsigned short plds[4][16 * 72]; //  9.2 KB
    __shared__ float bnp[2 * COUT];                           //  1 KB
    __shared__ float scs[2 * COUT];                           //  1 KB
    __shared__ float ls[4], lq[4];

    cg::grid_group grid = cg::this_grid();

    const int tid  = threadIdx.x;
    const int wv   = tid >> 6;
    const int lane = tid & 63;
    const int ptc  = lane & 15;
    const int qg   = lane >> 4;
    const int pt4  = lane >> 2;
    const int q4   = lane & 3;
    const int swq  = ptc >> 1;              // read-side swizzle rotation
    const int Qg   = (q4 + (pt4 >> 1)) & 3; // quarter this lane DMAs
    const int G    = (int)gridDim.x;

    // ================= Phase A: transpose [B,C,N] -> fb [B*N][64] bf16 ======
    #pragma unroll 1
    for (int tile = blockIdx.x; tile < 1024; tile += G) {
        int b  = tile >> 8;
        int n0 = (tile & 255) << 6;
        const float* fp = feat + (size_t)b * CIN * NPTS;
        #pragma unroll
        for (int r = 0; r < CIN; r += 4) {
            int c = r + wv;
            u.t[c][lane] = fp[(size_t)c * NPTS + n0 + lane];  // coalesced along n
        }
        __syncthreads();
        unsigned short* ob = fb + (size_t)(b * NPTS + n0) * CIN;
        #pragma unroll
        for (int r = 0; r < CIN; r += 4) {
            int x = r + wv;
            ob[(size_t)x * CIN + lane] = f2bf(u.t[lane][x]);
        }
        __syncthreads();
    }
    bnp[tid] = 0.f;

    // weight A-fragments in registers (R2-proven): A[m=ptc][k=qg*8+j(+32ks)]
    short8 wmF[4][2], wcF[8][2];
    #pragma unroll
    for (int mt = 0; mt < 4; ++mt)
        #pragma unroll
        for (int ks = 0; ks < 2; ++ks) {
            const float* p = Wm + (size_t)(mt * 16 + ptc) * CIN + qg * 8 + ks * 32;
            short8 v;
            #pragma unroll
            for (int j = 0; j < 8; ++j) v[j] = (short)f2bf(p[j]);
            wmF[mt][ks] = v;
        }
    #pragma unroll
    for (int mt = 0; mt < 8; ++mt)
        #pragma unroll
        for (int ks = 0; ks < 2; ++ks) {
            const float* p = Wc + (size_t)(mt * 16 + ptc) * CIN + qg * 8 + ks * 32;
            short8 v;
            #pragma unroll
            for (int j = 0; j < 8; ++j) v[j] = (short)f2bf(p[j]);
            wcF[mt][ks] = v;
        }

    grid.sync();   // fb complete device-wide

    // ================= Phase B: gather + attention + linear =================
    #pragma unroll 1
    for (int g = blockIdx.x * 4 + wv; g < NGRP; g += G * 4) {
        i32x4 iv = *(const i32x4*)(nidx + (size_t)g * 256 + lane * 4);

        auto issue = [&](int k, int bf) {
            int id = __shfl(iv[k & 3], (lane & ~3) | (k >> 2));
            const unsigned short* gp = fb + (size_t)id * CIN + Qg * 8;
            __builtin_amdgcn_global_load_lds(
                (const __attribute__((address_space(1))) unsigned int*)(const void*)gp,
                (__attribute__((address_space(3))) unsigned int*)(void*)&u.spir[wv][bf][0],
                16, 0, 0);
            __builtin_amdgcn_global_load_lds(
                (const __attribute__((address_space(1))) unsigned int*)(const void*)(gp + 32),
                (__attribute__((address_space(3))) unsigned int*)(void*)&u.spir[wv][bf][512],
                16, 0, 0);
        };

        issue(0, 0);
        issue(1, 1);

        f32x4 acc2[8];
        #pragma unroll
        for (int i = 0; i < 8; ++i) acc2[i] = (f32x4){0.f, 0.f, 0.f, 0.f};

        #pragma unroll
        for (int k = 0; k < KNB; ++k) {
            const int bf = k & 1;
            if (k < KNB - 1) WAITVM(2); else WAITVM(0);    // buf k landed
            __asm__ volatile("" ::: "memory");

            // ---- phase 1: score^T[d, pt] = Wm x spir^T ----
            const int so = (qg - swq) & 3;                 // swizzled slot
            short8 b1_0 = *(const short8*)&u.spir[wv][bf][      ptc * 32 + so * 8];
            short8 b1_1 = *(const short8*)&u.spir[wv][bf][512 + ptc * 32 + so * 8];
            f32x4 zero4 = (f32x4){0.f, 0.f, 0.f, 0.f};
            f32x4 a1[4];
            #pragma unroll
            for (int mt = 0; mt < 4; ++mt) {
                f32x4 t0 = __builtin_amdgcn_mfma_f32_16x16x32_bf16(wmF[mt][0], b1_0, zero4, 0, 0, 0);
                a1[mt]   = __builtin_amdgcn_mfma_f32_16x16x32_bf16(wmF[mt][1], b1_1, t0,    0, 0, 0);
            }

            // ---- softmax over d: 16 in-lane exps + xor16/xor32 ----
            float e[16], s = 0.f;
            #pragma unroll
            for (int mt = 0; mt < 4; ++mt)
                #pragma unroll
                for (int r = 0; r < 4; ++r) {
                    float x = __expf(a1[mt][r]);
                    e[mt * 4 + r] = x;
                    s += x;
                }
            s += __shfl_xor(s, 16);
            s += __shfl_xor(s, 32);
            float inv = __builtin_amdgcn_rcpf(s);

            // ---- P = attn (.) spir -> plds (bf16, B-layout staging) ----
            #pragma unroll
            for (int mt = 0; mt < 4; ++mt) {
                const int h  = mt >> 1;
                const int Qh = (mt & 1) * 2 + (qg >> 1);
                const int sl = (Qh - swq) & 3;
                u32x2 sv = *(const u32x2*)&u.spir[wv][bf]
                    [h * 512 + ptc * 32 + sl * 8 + (qg & 1) * 4];
                unsigned lo = sv[0], hi = sv[1];
                float p0 = bf2f((unsigned short)lo)         * (e[mt * 4 + 0] * inv);
                float p1 = bf2f((unsigned short)(lo >> 16)) * (e[mt * 4 + 1] * inv);
                float p2 = bf2f((unsigned short)hi)         * (e[mt * 4 + 2] * inv);
                float p3 = bf2f((unsigned short)(hi >> 16)) * (e[mt * 4 + 3] * inv);
                unsigned w0 = ((__float_as_uint(p0) + 0x8000u) >> 16) |
                              ((__float_as_uint(p1) + 0x8000u) & 0xFFFF0000u);
                unsigned w1 = ((__float_as_uint(p2) + 0x8000u) >> 16) |
                              ((__float_as_uint(p3) + 0x8000u) & 0xFFFF0000u);
                *(u32x2*)&plds[wv][ptc * 72 + mt * 16 + qg * 4] = (u32x2){w0, w1};
            }

            short8 b2_0 = *(const short8*)&plds[wv][ptc * 72 +      qg * 8];
            short8 b2_1 = *(const short8*)&plds[wv][ptc * 72 + 32 + qg * 8];

            if (k < KNB - 2) issue(k + 2, bf);             // dbuf refill

            // ---- phase 2: D[o, pt] += Wc x P_k ----
            #pragma unroll
            for (int mt = 0; mt < 8; ++mt) {
                acc2[mt] = __builtin_amdgcn_mfma_f32_16x16x32_bf16(wcF[mt][0], b2_0, acc2[mt], 0, 0, 0);
                acc2[mt] = __builtin_amdgcn_mfma_f32_16x16x32_bf16(wcF[mt][1], b2_1, acc2[mt], 0, 0, 0);
            }
        }

        // ---- epilogue: store pre-BN out + BN partials (shuffle + LDS atomic)
        int p0 = g << 4;
        int b  = p0 >> 14;
        int nn = (p0 & (NPTS - 1)) + ptc;
        float* ob = out + (((size_t)(b * COUT)) << 14) + nn;
        #pragma unroll
        for (int mt = 0; mt < 8; ++mt)
            #pragma unroll
            for (int r = 0; r < 4; ++r)
                ob[((size_t)(mt * 16 + qg * 4 + r)) << 14] = acc2[mt][r];

        #pragma unroll
        for (int mt = 0; mt < 8; ++mt)
            #pragma unroll
            for (int r = 0; r < 4; ++r) {
                float s = acc2[mt][r], q = s * s;
                #pragma unroll
                for (int off = 1; off <= 8; off <<= 1) {
                    s += __shfl_xor(s, off);
                    q += __shfl_xor(q, off);
                }
                if (ptc == 0) {
                    int o = mt * 16 + qg * 4 + r;
                    atomicAdd(&bnp[o], s);          // ds_add_f32, block-local
                    atomicAdd(&bnp[COUT + o], q);
                }
            }
    }

    __syncthreads();
    part[(size_t)blockIdx.x * 256 + tid] = bnp[tid];

    grid.sync();   // all partials visible

    // ================= Phase C: blocks 0..127 -> per-channel scale/shift ====
    if (blockIdx.x < COUT) {
        const int c = (int)blockIdx.x;
        float s = 0.f, q = 0.f;
        #pragma unroll 1
        for (int r = tid; r < G; r += 256) {
            s += part[(size_t)r * 256 + c];
            q += part[(size_t)r * 256 + COUT + c];
        }
        #pragma unroll
        for (int off = 32; off >= 1; off >>= 1) {
            s += __shfl_xor(s, off);
            q += __shfl_xor(q, off);
        }
        if (lane == 0) { ls[wv] = s; lq[wv] = q; }
        __syncthreads();
        if (tid == 0) {
            float ts = (ls[0] + ls[1]) + (ls[2] + ls[3]);
            float tq = (lq[0] + lq[1]) + (lq[2] + lq[3]);
            float mean = ts * (1.0f / BNP);
            float var  = tq * (1.0f / BNP) - mean * mean;
            float a = gamma[c] * rsqrtf(var + BN_EPS);
            scalesh[c]        = a;
            scalesh[COUT + c] = beta[c] - mean * a;
        }
    }

    grid.sync();   // scale/shift ready

    // ================= Phase D: apply BN in place on out [B][OUT][N] ========
    scs[tid] = scalesh[tid];
    __syncthreads();
    const int total4 = BATCH * COUT * NPTS / 4;   // 2,097,152
    #pragma unroll 1
    for (int i = (int)blockIdx.x * 256 + tid; i < total4; i += G * 256) {
        int ch = (i >> 12) & 127;
        float4 v = ((float4*)out)[i];
        float a = scs[ch], b2 = scs[COUT + ch];
        v.x = fmaf(v.x, a, b2); v.y = fmaf(v.y, a, b2);
        v.z = fmaf(v.z, a, b2); v.w = fmaf(v.w, a, b2);
        ((float4*)out)[i] = v;
    }
}

extern "C" void kernel_launch(void* const* d_in, const int* in_sizes, int n_in,
                              void* d_out, int out_size, void* d_ws, size_t ws_size,
                              hipStream_t stream)
{
    const float* feat  = (const float*)d_in[0];
    const int*   nidx  = (const int*)  d_in[1];
    // d_in[2] = permatrix (unused); d_in[5] = b_conv (exactly absorbed by BN)
    const float* Wm    = (const float*)d_in[3];
    const float* Wc    = (const float*)d_in[4];
    const float* gamma = (const float*)d_in[6];
    const float* beta  = (const float*)d_in[7];
    float* out = (float*)d_out;

    unsigned short* fb = (unsigned short*)d_ws;                        // 8.4 MB
    float* part    = (float*)((char*)d_ws + (size_t)BNP * CIN * 2);    // 512 KB max
    float* scalesh = part + (size_t)GRIDMAX * 256;                     // 256 floats

    // grid = what the runtime itself says is co-resident (capture-safe query)
    int occ = 0;
    (void)hipOccupancyMaxActiveBlocksPerMultiprocessor(&occ, (const void*)k_all,
                                                       256, 0);
    if (occ < 1) occ = 1;
    int grid = occ * 256;
    if (grid > GRIDMAX) grid = GRIDMAX;

    void* args[] = { (void*)&feat, (void*)&nidx, (void*)&Wm, (void*)&Wc,
                     (void*)&gamma, (void*)&beta, (void*)&fb, (void*)&part,
                     (void*)&scalesh, (void*)&out };
    (void)hipLaunchCooperativeKernel((const void*)k_all, dim3(grid), dim3(256),
                                     args, 0, stream);
}